// Round 3
// baseline (881.973 us; speedup 1.0000x reference)
//
#include <hip/hip_runtime.h>
#include <hip/hip_bf16.h>
#include <math.h>

typedef __hip_bfloat16 bf16;
typedef __attribute__((ext_vector_type(8))) short short8;
typedef __attribute__((ext_vector_type(4))) float f32x4;

#define MFMA16(A, B, C) __builtin_amdgcn_mfma_f32_16x16x32_bf16((A), (B), (C), 0, 0, 0)
#define NEG_BIG (-1e30f)

// fp32 -> bf16 round-to-nearest-even via bit ops (no API-name dependence)
static __device__ __forceinline__ unsigned short f32_to_bf16_rne(float f) {
    unsigned int u = __float_as_uint(f);
    unsigned int rnd = 0x7FFFu + ((u >> 16) & 1u);
    return (unsigned short)((u + rnd) >> 16);
}

// ---------------------------------------------------------------------------
// Kernel 0a: dtype probe. Interpret x's first 4096 u16 as bf16; count huge
// exponents. bf16 N(0,1) data -> ~0 hits; fp32 bits read as bf16 -> ~1000.
// ---------------------------------------------------------------------------
__global__ void dtype_probe(const unsigned short* __restrict__ x,
                            unsigned int* __restrict__ flag)
{
    __shared__ int cnt_s[256];
    const int tid = threadIdx.x;
    int c = 0;
    for (int i = tid; i < 4096; i += 256) {
        int e = (x[i] >> 7) & 0xFF;   // bf16 exponent field
        if (e >= 133) ++c;            // |v| >= 64
    }
    cnt_s[tid] = c;
    __syncthreads();
    for (int off = 128; off > 0; off >>= 1) {
        if (tid < off) cnt_s[tid] += cnt_s[tid + off];
        __syncthreads();
    }
    if (tid == 0) flag[0] = (cnt_s[0] > 32) ? 1u : 0u;  // 1 = inputs are fp32
}

// ---------------------------------------------------------------------------
// Kernel 0b: materialize canonical bf16 copy of an input tensor.
// flag==0: raw copy (already bf16). flag==1: fp32 -> bf16 RNE.
// nwords = output u32 words (= nelems/2).
// ---------------------------------------------------------------------------
__global__ __launch_bounds__(256) void convert_in(
    const void* __restrict__ src, unsigned int* __restrict__ dst,
    const unsigned int* __restrict__ flag, int nwords)
{
    int i = blockIdx.x * 256 + threadIdx.x;
    if (i >= nwords) return;
    if (flag[0] == 0u) {
        dst[i] = ((const unsigned int*)src)[i];
    } else {
        const float* f = (const float*)src;
        unsigned int lo = f32_to_bf16_rne(f[2 * i]);
        unsigned int hi = f32_to_bf16_rne(f[2 * i + 1]);
        dst[i] = (hi << 16) | lo;
    }
}

// ---------------------------------------------------------------------------
// Kernel 1: QKV projection GEMM (C = X * W^T) with fused RoPE epilogue.
// grid = (64 m-tiles, 48 = 3 weights x 16 n-tiles), block = 256 (4 waves).
// ---------------------------------------------------------------------------
__global__ __launch_bounds__(256) void gemm_qkv_rope(
    const bf16* __restrict__ X,
    const bf16* __restrict__ Wq, const bf16* __restrict__ Wk,
    const bf16* __restrict__ Wv,
    const int* __restrict__ pos,
    bf16* __restrict__ Qb, bf16* __restrict__ Kb, bf16* __restrict__ Vb)
{
    __shared__ __align__(16) short Xs[64 * 40];
    __shared__ __align__(16) short Ws[64 * 40];

    const int m0   = blockIdx.x * 64;
    const int wsel = blockIdx.y >> 4;            // 0=Q, 1=K, 2=V
    const int n0   = (blockIdx.y & 15) * 64;
    const bf16* W  = (wsel == 0) ? Wq : (wsel == 1) ? Wk : Wv;

    const int tid  = threadIdx.x;
    const int lane = tid & 63;
    const int wave = tid >> 6;
    const int wr   = wave >> 1, wc = wave & 1;
    const int srow = tid >> 2;
    const int sseg = tid & 3;
    const int fr   = lane & 15;
    const int fq   = lane >> 4;

    f32x4 acc00 = {0.f,0.f,0.f,0.f}, acc01 = {0.f,0.f,0.f,0.f};
    f32x4 acc10 = {0.f,0.f,0.f,0.f}, acc11 = {0.f,0.f,0.f,0.f};

    for (int k0 = 0; k0 < 1024; k0 += 32) {
        __syncthreads();
        *(short8*)&Xs[srow * 40 + sseg * 8] =
            *(const short8*)(X + (m0 + srow) * 1024 + k0 + sseg * 8);
        *(short8*)&Ws[srow * 40 + sseg * 8] =
            *(const short8*)(W + (n0 + srow) * 1024 + k0 + sseg * 8);
        __syncthreads();

        short8 a0 = *(const short8*)&Xs[(wr * 32 +      fr) * 40 + fq * 8];
        short8 a1 = *(const short8*)&Xs[(wr * 32 + 16 + fr) * 40 + fq * 8];
        short8 b0 = *(const short8*)&Ws[(wc * 32 +      fr) * 40 + fq * 8];
        short8 b1 = *(const short8*)&Ws[(wc * 32 + 16 + fr) * 40 + fq * 8];
        acc00 = MFMA16(a0, b0, acc00);
        acc01 = MFMA16(a0, b1, acc01);
        acc10 = MFMA16(a1, b0, acc10);
        acc11 = MFMA16(a1, b1, acc11);
    }

    // C/D layout: col = lane&15, row = (lane>>4)*4 + reg
    for (int i = 0; i < 2; ++i) {
        for (int j = 0; j < 2; ++j) {
            f32x4 a = (i == 0) ? ((j == 0) ? acc00 : acc01)
                               : ((j == 0) ? acc10 : acc11);
            for (int r = 0; r < 4; ++r) {
                int gm = m0 + wr * 32 + i * 16 + fq * 4 + r;  // b*2048+s
                int gn = n0 + wc * 32 + j * 16 + fr;          // 0..1023
                float v = a[r];
                int b = gm >> 11, s = gm & 2047;
                int h = gn >> 6,  d = gn & 63;
                float outv;
                float partner = __shfl_xor(v, 1);  // other half of RoPE pair
                if (wsel < 2) {
                    int   p    = d >> 1;
                    float freq = __expf((float)p * -0.28782313662425575f);
                    float ang  = (float)pos[s] * freq;
                    float sn, c;
                    sincosf(ang, &sn, &c);
                    outv = ((d & 1) == 0) ? (c * v - sn * partner)
                                          : (sn * partner + c * v);
                } else {
                    outv = v;
                }
                int idx = ((b * 16 + h) * 2048 + s) * 64 + d;  // [b,h,s,d]
                if (wsel == 0)      Qb[idx] = __float2bfloat16(outv);
                else if (wsel == 1) Kb[idx] = __float2bfloat16(outv);
                else                Vb[idx] = __float2bfloat16(outv);
            }
        }
    }
}

// ---------------------------------------------------------------------------
// Kernel 2: causal flash attention, fp32 vector math.
// All exp args clamped to >= -80: no huge-magnitude values ever reach exp.
// grid = (32 q-tiles, 16 heads, 2 batch), block = 256.
// ---------------------------------------------------------------------------
__global__ __launch_bounds__(256) void flash_attn(
    const bf16* __restrict__ Qb, const bf16* __restrict__ Kb,
    const bf16* __restrict__ Vb, bf16* __restrict__ ctx)
{
    const int qt = blockIdx.x, h = blockIdx.y, b = blockIdx.z;
    __shared__ float Qs[64][65];
    __shared__ float KPs[64][65];
    __shared__ float Vs[64][65];

    const int tid = threadIdx.x;
    const int tx = tid & 15, ty = tid >> 4;
    const int bh = b * 16 + h;

    {
        const bf16* Qp = Qb + (bh * 2048 + qt * 64) * 64;
        int row = tid >> 2, seg = (tid & 3) * 16;
        for (int e = 0; e < 16; ++e)
            Qs[row][seg + e] = __bfloat162float(Qp[row * 64 + seg + e]);
    }

    float o[4][4] = {};
    float mi[4], li[4];
    for (int i = 0; i < 4; ++i) { mi[i] = NEG_BIG; li[i] = 0.f; }

    for (int kt = 0; kt <= qt; ++kt) {
        __syncthreads();  // prior PV reads of KPs/Vs done
        {
            const bf16* Kp = Kb + (bh * 2048 + kt * 64) * 64;
            const bf16* Vp = Vb + (bh * 2048 + kt * 64) * 64;
            int row = tid >> 2, seg = (tid & 3) * 16;
            for (int e = 0; e < 16; ++e) {
                KPs[row][seg + e] = __bfloat162float(Kp[row * 64 + seg + e]);
                Vs[row][seg + e]  = __bfloat162float(Vp[row * 64 + seg + e]);
            }
        }
        __syncthreads();

        // S = Q K^T / sqrt(64), causal mask with finite sentinel
        float s[4][4] = {};
        for (int kk = 0; kk < 64; ++kk) {
            float qv[4], kv[4];
            for (int i = 0; i < 4; ++i) qv[i] = Qs[ty * 4 + i][kk];
            for (int j = 0; j < 4; ++j) kv[j] = KPs[tx * 4 + j][kk];
            for (int i = 0; i < 4; ++i)
                for (int j = 0; j < 4; ++j) s[i][j] += qv[i] * kv[j];
        }
        for (int i = 0; i < 4; ++i)
            for (int j = 0; j < 4; ++j) {
                s[i][j] *= 0.125f;
                if (kt * 64 + tx * 4 + j > qt * 64 + ty * 4 + i)
                    s[i][j] = NEG_BIG;
            }

        // online softmax (row stats across the 16-lane tx group)
        float mnew[4], alpha[4];
        for (int i = 0; i < 4; ++i) {
            float rm = fmaxf(fmaxf(s[i][0], s[i][1]), fmaxf(s[i][2], s[i][3]));
            for (int off = 1; off < 16; off <<= 1)
                rm = fmaxf(rm, __shfl_xor(rm, off));
            mnew[i]  = fmaxf(mi[i], rm);
            alpha[i] = __expf(fmaxf(mi[i] - mnew[i], -80.f));  // <=1.8e-35 on first tile
            mi[i]    = mnew[i];
        }
        for (int i = 0; i < 4; ++i) {
            float acc = 0.f;
            for (int j = 0; j < 4; ++j) {
                s[i][j] = __expf(fmaxf(s[i][j] - mnew[i], -80.f));  // masked -> ~0
                acc += s[i][j];
            }
            for (int off = 1; off < 16; off <<= 1)
                acc += __shfl_xor(acc, off);
            li[i] = li[i] * alpha[i] + acc;
            for (int j = 0; j < 4; ++j) o[i][j] *= alpha[i];
        }

        __syncthreads();  // all score reads of KPs done before P overwrite
        for (int i = 0; i < 4; ++i)
            for (int j = 0; j < 4; ++j)
                KPs[ty * 4 + i][tx * 4 + j] = s[i][j];
        __syncthreads();

        // O += P V
        for (int kk = 0; kk < 64; ++kk) {
            float pv[4], vv[4];
            for (int i = 0; i < 4; ++i) pv[i] = KPs[ty * 4 + i][kk];
            for (int j = 0; j < 4; ++j) vv[j] = Vs[kk][tx * 4 + j];
            for (int i = 0; i < 4; ++i)
                for (int j = 0; j < 4; ++j) o[i][j] += pv[i] * vv[j];
        }
    }

    for (int i = 0; i < 4; ++i) {
        float inv = 1.f / li[i];
        int srow = qt * 64 + ty * 4 + i;
        for (int j = 0; j < 4; ++j)
            ctx[(b * 2048 + srow) * 1024 + h * 64 + tx * 4 + j] =
                __float2bfloat16(o[i][j] * inv);
    }
}

// ---------------------------------------------------------------------------
// Kernel 3: output projection (out = ctx * Wo^T); store dtype per flag.
// ---------------------------------------------------------------------------
__global__ __launch_bounds__(256) void gemm_out(
    const bf16* __restrict__ A, const bf16* __restrict__ W,
    void* __restrict__ out, const unsigned int* __restrict__ flag)
{
    __shared__ __align__(16) short As[64 * 40];
    __shared__ __align__(16) short Ws[64 * 40];

    const int m0 = blockIdx.x * 64;
    const int n0 = blockIdx.y * 64;
    const int tid  = threadIdx.x;
    const int lane = tid & 63;
    const int wave = tid >> 6;
    const int wr = wave >> 1, wc = wave & 1;
    const int srow = tid >> 2, sseg = tid & 3;
    const int fr = lane & 15, fq = lane >> 4;
    const unsigned int fl = flag[0];

    f32x4 acc00 = {0.f,0.f,0.f,0.f}, acc01 = {0.f,0.f,0.f,0.f};
    f32x4 acc10 = {0.f,0.f,0.f,0.f}, acc11 = {0.f,0.f,0.f,0.f};

    for (int k0 = 0; k0 < 1024; k0 += 32) {
        __syncthreads();
        *(short8*)&As[srow * 40 + sseg * 8] =
            *(const short8*)(A + (m0 + srow) * 1024 + k0 + sseg * 8);
        *(short8*)&Ws[srow * 40 + sseg * 8] =
            *(const short8*)(W + (n0 + srow) * 1024 + k0 + sseg * 8);
        __syncthreads();
        short8 a0 = *(const short8*)&As[(wr * 32 +      fr) * 40 + fq * 8];
        short8 a1 = *(const short8*)&As[(wr * 32 + 16 + fr) * 40 + fq * 8];
        short8 b0 = *(const short8*)&Ws[(wc * 32 +      fr) * 40 + fq * 8];
        short8 b1 = *(const short8*)&Ws[(wc * 32 + 16 + fr) * 40 + fq * 8];
        acc00 = MFMA16(a0, b0, acc00);
        acc01 = MFMA16(a0, b1, acc01);
        acc10 = MFMA16(a1, b0, acc10);
        acc11 = MFMA16(a1, b1, acc11);
    }

    for (int i = 0; i < 2; ++i)
        for (int j = 0; j < 2; ++j) {
            f32x4 a = (i == 0) ? ((j == 0) ? acc00 : acc01)
                               : ((j == 0) ? acc10 : acc11);
            for (int r = 0; r < 4; ++r) {
                int gm = m0 + wr * 32 + i * 16 + fq * 4 + r;
                int gn = n0 + wc * 32 + j * 16 + fr;
                int idx = gm * 1024 + gn;
                if (fl == 0u) ((bf16*)out)[idx]  = __float2bfloat16(a[r]);
                else          ((float*)out)[idx] = a[r];
            }
        }
}

// ---------------------------------------------------------------------------
extern "C" void kernel_launch(void* const* d_in, const int* in_sizes, int n_in,
                              void* d_out, int out_size, void* d_ws, size_t ws_size,
                              hipStream_t stream)
{
    const void* x_raw  = d_in[0];
    const void* Wq_raw = d_in[1];
    const void* Wk_raw = d_in[2];
    const void* Wv_raw = d_in[3];
    const void* Wo_raw = d_in[4];
    const int*  pos    = (const int*)d_in[5];

    // workspace layout (bytes)
    char* ws = (char*)d_ws;
    unsigned int* flag = (unsigned int*)ws;                   // 256 B reserved
    bf16* Xc  = (bf16*)(ws + 256);                            // 8 MB
    bf16* Wqc = (bf16*)(ws + 256 + 8388608);                  // 2 MB
    bf16* Wkc = (bf16*)(ws + 256 + 8388608 + 2097152);
    bf16* Wvc = (bf16*)(ws + 256 + 8388608 + 2 * 2097152);
    bf16* Woc = (bf16*)(ws + 256 + 8388608 + 3 * 2097152);
    bf16* Qb  = (bf16*)(ws + 256 + 8388608 + 4 * 2097152);    // 8 MB
    bf16* Kb  = Qb + 4194304;
    bf16* Vb  = Kb + 4194304;
    bf16* ctx = Vb + 4194304;

    dtype_probe<<<1, 256, 0, stream>>>((const unsigned short*)x_raw, flag);

    convert_in<<<2097152 / 256, 256, 0, stream>>>(x_raw,  (unsigned int*)Xc,  flag, 2097152);
    convert_in<<< 524288 / 256, 256, 0, stream>>>(Wq_raw, (unsigned int*)Wqc, flag,  524288);
    convert_in<<< 524288 / 256, 256, 0, stream>>>(Wk_raw, (unsigned int*)Wkc, flag,  524288);
    convert_in<<< 524288 / 256, 256, 0, stream>>>(Wv_raw, (unsigned int*)Wvc, flag,  524288);
    convert_in<<< 524288 / 256, 256, 0, stream>>>(Wo_raw, (unsigned int*)Woc, flag,  524288);

    gemm_qkv_rope<<<dim3(64, 48), 256, 0, stream>>>(Xc, Wqc, Wkc, Wvc, pos, Qb, Kb, Vb);
    flash_attn<<<dim3(32, 16, 2), 256, 0, stream>>>(Qb, Kb, Vb, ctx);
    gemm_out<<<dim3(64, 16), 256, 0, stream>>>(ctx, Woc, d_out, flag);
}

// Round 5
// 307.688 us; speedup vs baseline: 2.8665x; 2.8665x over previous
//
#include <hip/hip_runtime.h>
#include <hip/hip_bf16.h>
#include <math.h>

typedef __hip_bfloat16 bf16;
typedef __attribute__((ext_vector_type(8))) short short8;
typedef __attribute__((ext_vector_type(4))) float f32x4;

#define MFMA16(A, B, C) __builtin_amdgcn_mfma_f32_16x16x32_bf16((A), (B), (C), 0, 0, 0)
#define NEG_BIG (-1e30f)

// fp32 -> bf16 round-to-nearest-even via bit ops
static __device__ __forceinline__ unsigned short f32_to_bf16_rne(float f) {
    unsigned int u = __float_as_uint(f);
    unsigned int rnd = 0x7FFFu + ((u >> 16) & 1u);
    return (unsigned short)((u + rnd) >> 16);
}

// ---------------------------------------------------------------------------
// Kernel 0a: dtype probe (bf16 vs fp32 input bits) -> flag in ws.
// ---------------------------------------------------------------------------
__global__ void dtype_probe(const unsigned short* __restrict__ x,
                            unsigned int* __restrict__ flag)
{
    __shared__ int cnt_s[256];
    const int tid = threadIdx.x;
    int c = 0;
    for (int i = tid; i < 4096; i += 256) {
        int e = (x[i] >> 7) & 0xFF;
        if (e >= 133) ++c;
    }
    cnt_s[tid] = c;
    __syncthreads();
    for (int off = 128; off > 0; off >>= 1) {
        if (tid < off) cnt_s[tid] += cnt_s[tid + off];
        __syncthreads();
    }
    if (tid == 0) flag[0] = (cnt_s[0] > 32) ? 1u : 0u;  // 1 = inputs are fp32
}

// ---------------------------------------------------------------------------
// Kernel 0b: canonical bf16 copy (raw copy or fp32->bf16 RNE per flag).
// ---------------------------------------------------------------------------
__global__ __launch_bounds__(256) void convert_in(
    const void* __restrict__ src, unsigned int* __restrict__ dst,
    const unsigned int* __restrict__ flag, int nwords)
{
    int i = blockIdx.x * 256 + threadIdx.x;
    if (i >= nwords) return;
    if (flag[0] == 0u) {
        dst[i] = ((const unsigned int*)src)[i];
    } else {
        const float* f = (const float*)src;
        unsigned int lo = f32_to_bf16_rne(f[2 * i]);
        unsigned int hi = f32_to_bf16_rne(f[2 * i + 1]);
        dst[i] = (hi << 16) | lo;
    }
}

// ---------------------------------------------------------------------------
// Kernel 1: QKV projection GEMM (C = X * W^T) with fused RoPE epilogue.
// Q,K written [b,h,s,d]; V written TRANSPOSED [b,h,d,s] for the PV MFMA.
// LDS tiles here are 64 x 32 (BK=32): stride 40 is correct FOR THIS KERNEL.
// ---------------------------------------------------------------------------
__global__ __launch_bounds__(256) void gemm_qkv_rope(
    const bf16* __restrict__ X,
    const bf16* __restrict__ Wq, const bf16* __restrict__ Wk,
    const bf16* __restrict__ Wv,
    const int* __restrict__ pos,
    bf16* __restrict__ Qb, bf16* __restrict__ Kb, bf16* __restrict__ Vt)
{
    __shared__ __align__(16) short Xs[64 * 40];
    __shared__ __align__(16) short Ws[64 * 40];

    const int m0   = blockIdx.x * 64;
    const int wsel = blockIdx.y >> 4;            // 0=Q, 1=K, 2=V
    const int n0   = (blockIdx.y & 15) * 64;
    const bf16* W  = (wsel == 0) ? Wq : (wsel == 1) ? Wk : Wv;

    const int tid  = threadIdx.x;
    const int lane = tid & 63;
    const int wave = tid >> 6;
    const int wr   = wave >> 1, wc = wave & 1;
    const int srow = tid >> 2;
    const int sseg = tid & 3;
    const int fr   = lane & 15;
    const int fq   = lane >> 4;

    f32x4 acc00 = {0.f,0.f,0.f,0.f}, acc01 = {0.f,0.f,0.f,0.f};
    f32x4 acc10 = {0.f,0.f,0.f,0.f}, acc11 = {0.f,0.f,0.f,0.f};

    for (int k0 = 0; k0 < 1024; k0 += 32) {
        __syncthreads();
        *(short8*)&Xs[srow * 40 + sseg * 8] =
            *(const short8*)(X + (m0 + srow) * 1024 + k0 + sseg * 8);
        *(short8*)&Ws[srow * 40 + sseg * 8] =
            *(const short8*)(W + (n0 + srow) * 1024 + k0 + sseg * 8);
        __syncthreads();

        short8 a0 = *(const short8*)&Xs[(wr * 32 +      fr) * 40 + fq * 8];
        short8 a1 = *(const short8*)&Xs[(wr * 32 + 16 + fr) * 40 + fq * 8];
        short8 b0 = *(const short8*)&Ws[(wc * 32 +      fr) * 40 + fq * 8];
        short8 b1 = *(const short8*)&Ws[(wc * 32 + 16 + fr) * 40 + fq * 8];
        acc00 = MFMA16(a0, b0, acc00);
        acc01 = MFMA16(a0, b1, acc01);
        acc10 = MFMA16(a1, b0, acc10);
        acc11 = MFMA16(a1, b1, acc11);
    }

    for (int i = 0; i < 2; ++i) {
        for (int j = 0; j < 2; ++j) {
            f32x4 a = (i == 0) ? ((j == 0) ? acc00 : acc01)
                               : ((j == 0) ? acc10 : acc11);
            for (int r = 0; r < 4; ++r) {
                int gm = m0 + wr * 32 + i * 16 + fq * 4 + r;  // b*2048+s
                int gn = n0 + wc * 32 + j * 16 + fr;          // 0..1023
                float v = a[r];
                int b = gm >> 11, s = gm & 2047;
                int h = gn >> 6,  d = gn & 63;
                float outv;
                float partner = __shfl_xor(v, 1);
                if (wsel < 2) {
                    int   p    = d >> 1;
                    float freq = __expf((float)p * -0.28782313662425575f);
                    float ang  = (float)pos[s] * freq;
                    float sn, c;
                    sincosf(ang, &sn, &c);
                    outv = ((d & 1) == 0) ? (c * v - sn * partner)
                                          : (sn * partner + c * v);
                } else {
                    outv = v;
                }
                if (wsel == 0)
                    Qb[((b * 16 + h) * 2048 + s) * 64 + d] = __float2bfloat16(outv);
                else if (wsel == 1)
                    Kb[((b * 16 + h) * 2048 + s) * 64 + d] = __float2bfloat16(outv);
                else  // V transposed: [b,h,d,s]
                    Vt[((b * 16 + h) * 64 + d) * 2048 + s] = __float2bfloat16(outv);
            }
        }
    }
}

// ---------------------------------------------------------------------------
// Kernel 2: causal flash attention, MFMA bf16.
// grid = (32 qt, 16 h, 2 b), block = 256 (4 waves).
// 64x64 tiles -> LDS row stride 72 shorts (64 cols + 8 pad; 144 B rows,
// 16B-aligned; row-to-row bank offset 4 mod 32 -> worst case free 2-way).
// ---------------------------------------------------------------------------
#define FS 72

__global__ __launch_bounds__(256) void flash_attn(
    const bf16* __restrict__ Qb, const bf16* __restrict__ Kb,
    const bf16* __restrict__ Vt, bf16* __restrict__ ctx)
{
    const int qt = 31 - blockIdx.x;   // long blocks dispatch first
    const int h = blockIdx.y, b = blockIdx.z;
    const int bh = b * 16 + h;

    __shared__ __align__(16) short Ks[64 * FS];   // [key][d]
    __shared__ __align__(16) short Vs[64 * FS];   // [d][key]  (V^T tile)
    __shared__ __align__(16) short Ps[64 * FS];   // [q_row][key]

    const int tid  = threadIdx.x;
    const int lane = tid & 63;
    const int wave = tid >> 6;
    const int m = lane & 15;          // fragment row/col
    const int q = lane >> 4;          // quad
    const int srow = tid >> 2;        // staging row 0..63
    const int sseg = tid & 3;         // staging 8-col segment 0..3

    // Q fragments, persistent: A[m][k=q*8+j], rows wave*16+m
    const bf16* Qp = Qb + (bh * 2048 + qt * 64 + wave * 16 + m) * 64;
    short8 qf0 = *(const short8*)(Qp + q * 8);
    short8 qf1 = *(const short8*)(Qp + 32 + q * 8);

    f32x4 oacc[4];
    for (int nb = 0; nb < 4; ++nb) oacc[nb] = (f32x4){0.f,0.f,0.f,0.f};
    float mi[4], li[4];
    for (int r = 0; r < 4; ++r) { mi[r] = NEG_BIG; li[r] = 0.f; }

    const bf16* Kbase = Kb + bh * 2048 * 64;
    const bf16* Vbase = Vt + bh * 64 * 2048;

    for (int kt = 0; kt <= qt; ++kt) {
        __syncthreads();  // previous tile's K/V reads complete
        {
            const bf16* Kp = Kbase + kt * 64 * 64;
            const bf16* Vp = Vbase + kt * 64;
            *(short8*)&Ks[srow * FS + sseg * 8] =
                *(const short8*)(Kp + srow * 64 + sseg * 8);
            *(short8*)&Ks[srow * FS + sseg * 8 + 32] =
                *(const short8*)(Kp + srow * 64 + sseg * 8 + 32);
            *(short8*)&Vs[srow * FS + sseg * 8] =
                *(const short8*)(Vp + srow * 2048 + sseg * 8);
            *(short8*)&Vs[srow * FS + sseg * 8 + 32] =
                *(const short8*)(Vp + srow * 2048 + sseg * 8 + 32);
        }
        __syncthreads();

        // ---- S = Q K^T  (C layout: row = q*4+r, col = nb*16+m) ----
        f32x4 sacc[4];
        for (int nb = 0; nb < 4; ++nb) sacc[nb] = (f32x4){0.f,0.f,0.f,0.f};
        for (int nb = 0; nb < 4; ++nb) {
            short8 kf0 = *(const short8*)&Ks[(nb * 16 + m) * FS + q * 8];
            short8 kf1 = *(const short8*)&Ks[(nb * 16 + m) * FS + 32 + q * 8];
            sacc[nb] = MFMA16(qf0, kf0, sacc[nb]);
            sacc[nb] = MFMA16(qf1, kf1, sacc[nb]);
        }

        // ---- scale + causal mask (diagonal tile only) ----
        const bool diag = (kt == qt);
        for (int nb = 0; nb < 4; ++nb)
            for (int r = 0; r < 4; ++r) {
                float sv = sacc[nb][r] * 0.125f;
                if (diag && (nb * 16 + m) > (wave * 16 + q * 4 + r))
                    sv = NEG_BIG;
                sacc[nb][r] = sv;
            }

        // ---- online softmax (16-lane quad shuffles; lane's rows = q*4+r) ----
        float mnew[4], alpha[4];
        for (int r = 0; r < 4; ++r) {
            float rm = fmaxf(fmaxf(sacc[0][r], sacc[1][r]),
                             fmaxf(sacc[2][r], sacc[3][r]));
            for (int off = 1; off < 16; off <<= 1)
                rm = fmaxf(rm, __shfl_xor(rm, off));
            mnew[r]  = fmaxf(mi[r], rm);
            alpha[r] = __expf(fmaxf(mi[r] - mnew[r], -80.f));
            mi[r]    = mnew[r];
        }
        for (int r = 0; r < 4; ++r) {
            float acc = 0.f;
            for (int nb = 0; nb < 4; ++nb) {
                float p = __expf(fmaxf(sacc[nb][r] - mnew[r], -80.f));
                sacc[nb][r] = p;
                acc += p;
            }
            for (int off = 1; off < 16; off <<= 1)
                acc += __shfl_xor(acc, off);
            li[r] = li[r] * alpha[r] + acc;
            for (int nb = 0; nb < 4; ++nb) oacc[nb][r] *= alpha[r];
        }

        // ---- P (C layout) -> LDS -> A-frag layout ----
        // Each wave touches only its own 16 rows; in-wave DS ops execute in
        // order, and compiler alias analysis keeps write->read order on Ps.
        for (int nb = 0; nb < 4; ++nb)
            for (int r = 0; r < 4; ++r) {
                bf16 hv = __float2bfloat16(sacc[nb][r]);
                Ps[(wave * 16 + q * 4 + r) * FS + nb * 16 + m] = *(short*)&hv;
            }
        short8 pa0 = *(const short8*)&Ps[(wave * 16 + m) * FS + q * 8];
        short8 pa1 = *(const short8*)&Ps[(wave * 16 + m) * FS + 32 + q * 8];

        // ---- O += P V  (B-frag rows = d, k = key, from V^T tile) ----
        for (int nb = 0; nb < 4; ++nb) {
            short8 vf0 = *(const short8*)&Vs[(nb * 16 + m) * FS + q * 8];
            short8 vf1 = *(const short8*)&Vs[(nb * 16 + m) * FS + 32 + q * 8];
            oacc[nb] = MFMA16(pa0, vf0, oacc[nb]);
            oacc[nb] = MFMA16(pa1, vf1, oacc[nb]);
        }
    }

    // ---- normalize + write ctx [b, s, h*64+d] ----
    for (int r = 0; r < 4; ++r) {
        float inv = 1.f / li[r];
        int srowg = qt * 64 + wave * 16 + q * 4 + r;
        for (int nb = 0; nb < 4; ++nb)
            ctx[(b * 2048 + srowg) * 1024 + h * 64 + nb * 16 + m] =
                __float2bfloat16(oacc[nb][r] * inv);
    }
}

// ---------------------------------------------------------------------------
// Kernel 3: output projection (out = ctx * Wo^T); store dtype per flag.
// ---------------------------------------------------------------------------
__global__ __launch_bounds__(256) void gemm_out(
    const bf16* __restrict__ A, const bf16* __restrict__ W,
    void* __restrict__ out, const unsigned int* __restrict__ flag)
{
    __shared__ __align__(16) short As[64 * 40];
    __shared__ __align__(16) short Ws[64 * 40];

    const int m0 = blockIdx.x * 64;
    const int n0 = blockIdx.y * 64;
    const int tid  = threadIdx.x;
    const int lane = tid & 63;
    const int wave = tid >> 6;
    const int wr = wave >> 1, wc = wave & 1;
    const int srow = tid >> 2, sseg = tid & 3;
    const int fr = lane & 15, fq = lane >> 4;
    const unsigned int fl = flag[0];

    f32x4 acc00 = {0.f,0.f,0.f,0.f}, acc01 = {0.f,0.f,0.f,0.f};
    f32x4 acc10 = {0.f,0.f,0.f,0.f}, acc11 = {0.f,0.f,0.f,0.f};

    for (int k0 = 0; k0 < 1024; k0 += 32) {
        __syncthreads();
        *(short8*)&As[srow * 40 + sseg * 8] =
            *(const short8*)(A + (m0 + srow) * 1024 + k0 + sseg * 8);
        *(short8*)&Ws[srow * 40 + sseg * 8] =
            *(const short8*)(W + (n0 + srow) * 1024 + k0 + sseg * 8);
        __syncthreads();
        short8 a0 = *(const short8*)&As[(wr * 32 +      fr) * 40 + fq * 8];
        short8 a1 = *(const short8*)&As[(wr * 32 + 16 + fr) * 40 + fq * 8];
        short8 b0 = *(const short8*)&Ws[(wc * 32 +      fr) * 40 + fq * 8];
        short8 b1 = *(const short8*)&Ws[(wc * 32 + 16 + fr) * 40 + fq * 8];
        acc00 = MFMA16(a0, b0, acc00);
        acc01 = MFMA16(a0, b1, acc01);
        acc10 = MFMA16(a1, b0, acc10);
        acc11 = MFMA16(a1, b1, acc11);
    }

    for (int i = 0; i < 2; ++i)
        for (int j = 0; j < 2; ++j) {
            f32x4 a = (i == 0) ? ((j == 0) ? acc00 : acc01)
                               : ((j == 0) ? acc10 : acc11);
            for (int r = 0; r < 4; ++r) {
                int gm = m0 + wr * 32 + i * 16 + fq * 4 + r;
                int gn = n0 + wc * 32 + j * 16 + fr;
                int idx = gm * 1024 + gn;
                if (fl == 0u) ((bf16*)out)[idx]  = __float2bfloat16(a[r]);
                else          ((float*)out)[idx] = a[r];
            }
        }
}

// ---------------------------------------------------------------------------
extern "C" void kernel_launch(void* const* d_in, const int* in_sizes, int n_in,
                              void* d_out, int out_size, void* d_ws, size_t ws_size,
                              hipStream_t stream)
{
    const void* x_raw  = d_in[0];
    const void* Wq_raw = d_in[1];
    const void* Wk_raw = d_in[2];
    const void* Wv_raw = d_in[3];
    const void* Wo_raw = d_in[4];
    const int*  pos    = (const int*)d_in[5];

    char* ws = (char*)d_ws;
    unsigned int* flag = (unsigned int*)ws;                   // 256 B
    bf16* Xc  = (bf16*)(ws + 256);                            // 8 MB
    bf16* Wqc = (bf16*)(ws + 256 + 8388608);                  // 2 MB each
    bf16* Wkc = (bf16*)(ws + 256 + 8388608 + 2097152);
    bf16* Wvc = (bf16*)(ws + 256 + 8388608 + 2 * 2097152);
    bf16* Woc = (bf16*)(ws + 256 + 8388608 + 3 * 2097152);
    bf16* Qb  = (bf16*)(ws + 256 + 8388608 + 4 * 2097152);    // 8 MB each
    bf16* Kb  = Qb + 4194304;
    bf16* Vt  = Kb + 4194304;
    bf16* ctx = Vt + 4194304;

    dtype_probe<<<1, 256, 0, stream>>>((const unsigned short*)x_raw, flag);

    convert_in<<<2097152 / 256, 256, 0, stream>>>(x_raw,  (unsigned int*)Xc,  flag, 2097152);
    convert_in<<< 524288 / 256, 256, 0, stream>>>(Wq_raw, (unsigned int*)Wqc, flag,  524288);
    convert_in<<< 524288 / 256, 256, 0, stream>>>(Wk_raw, (unsigned int*)Wkc, flag,  524288);
    convert_in<<< 524288 / 256, 256, 0, stream>>>(Wv_raw, (unsigned int*)Wvc, flag,  524288);
    convert_in<<< 524288 / 256, 256, 0, stream>>>(Wo_raw, (unsigned int*)Woc, flag,  524288);

    gemm_qkv_rope<<<dim3(64, 48), 256, 0, stream>>>(Xc, Wqc, Wkc, Wvc, pos, Qb, Kb, Vt);
    flash_attn<<<dim3(32, 16, 2), 256, 0, stream>>>(Qb, Kb, Vt, ctx);
    gemm_out<<<dim3(64, 16), 256, 0, stream>>>(ctx, Woc, d_out, flag);
}

// Round 6
// 280.036 us; speedup vs baseline: 3.1495x; 1.0987x over previous
//
#include <hip/hip_runtime.h>
#include <hip/hip_bf16.h>
#include <math.h>

typedef __hip_bfloat16 bf16;
typedef __attribute__((ext_vector_type(8))) short short8;
typedef __attribute__((ext_vector_type(4))) float f32x4;

#define MFMA16(A, B, C) __builtin_amdgcn_mfma_f32_16x16x32_bf16((A), (B), (C), 0, 0, 0)
#define NEG_BIG (-1e30f)

// fp32 -> bf16 round-to-nearest-even via bit ops
static __device__ __forceinline__ unsigned short f32_to_bf16_rne(float f) {
    unsigned int u = __float_as_uint(f);
    unsigned int rnd = 0x7FFFu + ((u >> 16) & 1u);
    return (unsigned short)((u + rnd) >> 16);
}

// ---------------------------------------------------------------------------
// Kernel 0a: dtype probe (bf16 vs fp32 input bits) -> flag in ws.
// ---------------------------------------------------------------------------
__global__ void dtype_probe(const unsigned short* __restrict__ x,
                            unsigned int* __restrict__ flag)
{
    __shared__ int cnt_s[256];
    const int tid = threadIdx.x;
    int c = 0;
    for (int i = tid; i < 4096; i += 256) {
        int e = (x[i] >> 7) & 0xFF;
        if (e >= 133) ++c;
    }
    cnt_s[tid] = c;
    __syncthreads();
    for (int off = 128; off > 0; off >>= 1) {
        if (tid < off) cnt_s[tid] += cnt_s[tid + off];
        __syncthreads();
    }
    if (tid == 0) flag[0] = (cnt_s[0] > 32) ? 1u : 0u;  // 1 = inputs are fp32
}

// ---------------------------------------------------------------------------
// Kernel 0b: canonical bf16 copies of all 5 inputs in ONE launch.
// word index space: [0, 2097152) = X; then 4 x 524288 = Wq, Wk, Wv, Wo.
// ---------------------------------------------------------------------------
__global__ __launch_bounds__(256) void convert_all(
    const void* __restrict__ xs, const void* __restrict__ wq,
    const void* __restrict__ wk, const void* __restrict__ wv,
    const void* __restrict__ wo,
    unsigned int* __restrict__ Xc, unsigned int* __restrict__ Wqc,
    unsigned int* __restrict__ Wkc, unsigned int* __restrict__ Wvc,
    unsigned int* __restrict__ Woc,
    const unsigned int* __restrict__ flag)
{
    int i = blockIdx.x * 256 + threadIdx.x;  // 0 .. 4194303
    const void* src;
    unsigned int* dst;
    int off;
    if (i < 2097152) { src = xs; dst = Xc; off = i; }
    else {
        int j = i - 2097152;
        int t = j >> 19;          // 0..3
        off = j & 524287;
        src = (t == 0) ? wq : (t == 1) ? wk : (t == 2) ? wv : wo;
        dst = (t == 0) ? Wqc : (t == 1) ? Wkc : (t == 2) ? Wvc : Woc;
    }
    if (flag[0] == 0u) {
        dst[off] = ((const unsigned int*)src)[off];
    } else {
        const float* f = (const float*)src;
        unsigned int lo = f32_to_bf16_rne(f[2 * off]);
        unsigned int hi = f32_to_bf16_rne(f[2 * off + 1]);
        dst[off] = (hi << 16) | lo;
    }
}

// ---------------------------------------------------------------------------
// Kernel 1: QKV projection GEMM (C = X * W^T) with fused RoPE epilogue.
// Register-prefetch pipeline: tile k+1 loads overlap tile-k MFMA.
// Q,K written [b,h,s,d]; V written TRANSPOSED [b,h,d,s] via LDS transpose
// (coalesced 128 B row stores).
// ---------------------------------------------------------------------------
__global__ __launch_bounds__(256) void gemm_qkv_rope(
    const bf16* __restrict__ X,
    const bf16* __restrict__ Wq, const bf16* __restrict__ Wk,
    const bf16* __restrict__ Wv,
    const int* __restrict__ pos,
    bf16* __restrict__ Qb, bf16* __restrict__ Kb, bf16* __restrict__ Vt)
{
    __shared__ __align__(16) short Xs[64 * 40];
    __shared__ __align__(16) short Ws[64 * 40];
    __shared__ __align__(16) short Ts[64 * 72];   // V transpose staging

    const int m0   = blockIdx.x * 64;
    const int wsel = blockIdx.y >> 4;            // 0=Q, 1=K, 2=V
    const int n0   = (blockIdx.y & 15) * 64;
    const bf16* W  = (wsel == 0) ? Wq : (wsel == 1) ? Wk : Wv;

    const int tid  = threadIdx.x;
    const int lane = tid & 63;
    const int wave = tid >> 6;
    const int wr   = wave >> 1, wc = wave & 1;
    const int srow = tid >> 2;
    const int sseg = tid & 3;
    const int fr   = lane & 15;
    const int fq   = lane >> 4;

    const bf16* Xrow = X + (m0 + srow) * 1024 + sseg * 8;
    const bf16* Wrow = W + (n0 + srow) * 1024 + sseg * 8;

    f32x4 acc00 = {0.f,0.f,0.f,0.f}, acc01 = {0.f,0.f,0.f,0.f};
    f32x4 acc10 = {0.f,0.f,0.f,0.f}, acc11 = {0.f,0.f,0.f,0.f};

    short8 pxa = *(const short8*)(Xrow);   // prefetch k0 = 0
    short8 pwb = *(const short8*)(Wrow);

    for (int k0 = 0; k0 < 1024; k0 += 32) {
        __syncthreads();
        *(short8*)&Xs[srow * 40 + sseg * 8] = pxa;
        *(short8*)&Ws[srow * 40 + sseg * 8] = pwb;
        __syncthreads();
        if (k0 + 32 < 1024) {               // prefetch next tile (overlaps MFMA)
            pxa = *(const short8*)(Xrow + k0 + 32);
            pwb = *(const short8*)(Wrow + k0 + 32);
        }

        short8 a0 = *(const short8*)&Xs[(wr * 32 +      fr) * 40 + fq * 8];
        short8 a1 = *(const short8*)&Xs[(wr * 32 + 16 + fr) * 40 + fq * 8];
        short8 b0 = *(const short8*)&Ws[(wc * 32 +      fr) * 40 + fq * 8];
        short8 b1 = *(const short8*)&Ws[(wc * 32 + 16 + fr) * 40 + fq * 8];
        acc00 = MFMA16(a0, b0, acc00);
        acc01 = MFMA16(a0, b1, acc01);
        acc10 = MFMA16(a1, b0, acc10);
        acc11 = MFMA16(a1, b1, acc11);
    }

    const int bb = m0 >> 11;          // batch (block-uniform: tile within one b)
    const int s0 = m0 & 2047;
    const int hh = n0 >> 6;           // head  (block-uniform: 64-col tile = 1 head)

    if (wsel < 2) {
        // Q/K: RoPE epilogue, direct [b,h,s,d] stores
        for (int i = 0; i < 2; ++i)
            for (int j = 0; j < 2; ++j) {
                f32x4 a = (i == 0) ? ((j == 0) ? acc00 : acc01)
                                   : ((j == 0) ? acc10 : acc11);
                for (int r = 0; r < 4; ++r) {
                    int s = s0 + wr * 32 + i * 16 + fq * 4 + r;
                    int d = wc * 32 + j * 16 + fr;
                    float v = a[r];
                    float partner = __shfl_xor(v, 1);
                    int   p    = d >> 1;
                    float freq = __expf((float)p * -0.28782313662425575f);
                    float ang  = (float)pos[s] * freq;
                    float sn, c;
                    sincosf(ang, &sn, &c);
                    float outv = ((d & 1) == 0) ? (c * v - sn * partner)
                                                : (sn * partner + c * v);
                    bf16* dstb = (wsel == 0) ? Qb : Kb;
                    dstb[((bb * 16 + hh) * 2048 + s) * 64 + d] = __float2bfloat16(outv);
                }
            }
    } else {
        // V: transpose through LDS, then coalesced [b,h,d,s] row stores
        for (int i = 0; i < 2; ++i)
            for (int j = 0; j < 2; ++j) {
                f32x4 a = (i == 0) ? ((j == 0) ? acc00 : acc01)
                                   : ((j == 0) ? acc10 : acc11);
                for (int r = 0; r < 4; ++r) {
                    int ls = wr * 32 + i * 16 + fq * 4 + r;   // local s
                    int ld = wc * 32 + j * 16 + fr;           // local d
                    bf16 hv = __float2bfloat16(a[r]);
                    Ts[ld * 72 + ls] = *(short*)&hv;
                }
            }
        __syncthreads();
        int dd = tid >> 2;            // 0..63
        int sc = (tid & 3) * 16;      // 16-short chunk
        short8 t0 = *(const short8*)&Ts[dd * 72 + sc];
        short8 t1 = *(const short8*)&Ts[dd * 72 + sc + 8];
        bf16* vrow = Vt + ((bb * 16 + hh) * 64 + dd) * 2048 + s0 + sc;
        *(short8*)(vrow)     = t0;
        *(short8*)(vrow + 8) = t1;
    }
}

// ---------------------------------------------------------------------------
// Kernel 2: causal flash attention, MFMA bf16, register-prefetch pipeline.
// grid = (32 qt, 16 h, 2 b), block = 256 (4 waves).
// 64x64 tiles, LDS row stride 72 shorts (free 2-way bank aliasing).
// ---------------------------------------------------------------------------
#define FS 72

__global__ __launch_bounds__(256) void flash_attn(
    const bf16* __restrict__ Qb, const bf16* __restrict__ Kb,
    const bf16* __restrict__ Vt, bf16* __restrict__ ctx)
{
    const int qt = 31 - blockIdx.x;   // long blocks dispatch first
    const int h = blockIdx.y, b = blockIdx.z;
    const int bh = b * 16 + h;

    __shared__ __align__(16) short Ks[64 * FS];   // [key][d]
    __shared__ __align__(16) short Vs[64 * FS];   // [d][key]  (V^T tile)
    __shared__ __align__(16) short Ps[64 * FS];   // [q_row][key]

    const int tid  = threadIdx.x;
    const int lane = tid & 63;
    const int wave = tid >> 6;
    const int m = lane & 15;          // fragment row/col
    const int q = lane >> 4;          // quad
    const int srow = tid >> 2;        // staging row 0..63
    const int sseg = tid & 3;         // staging 8-col segment 0..3

    // Q fragments, persistent: A[m][k=q*8+j], rows wave*16+m
    const bf16* Qp = Qb + (bh * 2048 + qt * 64 + wave * 16 + m) * 64;
    short8 qf0 = *(const short8*)(Qp + q * 8);
    short8 qf1 = *(const short8*)(Qp + 32 + q * 8);

    f32x4 oacc[4];
    for (int nb = 0; nb < 4; ++nb) oacc[nb] = (f32x4){0.f,0.f,0.f,0.f};
    float mi[4], li[4];
    for (int r = 0; r < 4; ++r) { mi[r] = NEG_BIG; li[r] = 0.f; }

    const bf16* Krow = Kb + bh * 2048 * 64 + srow * 64   + sseg * 8;
    const bf16* Vrow = Vt + bh * 64 * 2048 + srow * 2048 + sseg * 8;

    // prefetch tile 0 into registers
    short8 kr0 = *(const short8*)(Krow);
    short8 kr1 = *(const short8*)(Krow + 32);
    short8 vr0 = *(const short8*)(Vrow);
    short8 vr1 = *(const short8*)(Vrow + 32);

    for (int kt = 0; kt <= qt; ++kt) {
        __syncthreads();  // previous tile's LDS reads complete
        *(short8*)&Ks[srow * FS + sseg * 8]      = kr0;
        *(short8*)&Ks[srow * FS + sseg * 8 + 32] = kr1;
        *(short8*)&Vs[srow * FS + sseg * 8]      = vr0;
        *(short8*)&Vs[srow * FS + sseg * 8 + 32] = vr1;
        __syncthreads();

        if (kt < qt) {    // prefetch next K/V tile; overlaps all compute below
            const bf16* Kn = Krow + (kt + 1) * 64 * 64;
            const bf16* Vn = Vrow + (kt + 1) * 64;
            kr0 = *(const short8*)(Kn);
            kr1 = *(const short8*)(Kn + 32);
            vr0 = *(const short8*)(Vn);
            vr1 = *(const short8*)(Vn + 32);
        }

        // ---- S = Q K^T  (C layout: row = q*4+r, col = nb*16+m) ----
        f32x4 sacc[4];
        for (int nb = 0; nb < 4; ++nb) sacc[nb] = (f32x4){0.f,0.f,0.f,0.f};
        for (int nb = 0; nb < 4; ++nb) {
            short8 kf0 = *(const short8*)&Ks[(nb * 16 + m) * FS + q * 8];
            short8 kf1 = *(const short8*)&Ks[(nb * 16 + m) * FS + 32 + q * 8];
            sacc[nb] = MFMA16(qf0, kf0, sacc[nb]);
            sacc[nb] = MFMA16(qf1, kf1, sacc[nb]);
        }

        // ---- scale + causal mask (diagonal tile only) ----
        const bool diag = (kt == qt);
        for (int nb = 0; nb < 4; ++nb)
            for (int r = 0; r < 4; ++r) {
                float sv = sacc[nb][r] * 0.125f;
                if (diag && (nb * 16 + m) > (wave * 16 + q * 4 + r))
                    sv = NEG_BIG;
                sacc[nb][r] = sv;
            }

        // ---- online softmax (16-lane quad shuffles; lane's rows = q*4+r) ----
        float mnew[4], alpha[4];
        for (int r = 0; r < 4; ++r) {
            float rm = fmaxf(fmaxf(sacc[0][r], sacc[1][r]),
                             fmaxf(sacc[2][r], sacc[3][r]));
            for (int off = 1; off < 16; off <<= 1)
                rm = fmaxf(rm, __shfl_xor(rm, off));
            mnew[r]  = fmaxf(mi[r], rm);
            alpha[r] = __expf(fmaxf(mi[r] - mnew[r], -80.f));
            mi[r]    = mnew[r];
        }
        for (int r = 0; r < 4; ++r) {
            float acc = 0.f;
            for (int nb = 0; nb < 4; ++nb) {
                float p = __expf(fmaxf(sacc[nb][r] - mnew[r], -80.f));
                sacc[nb][r] = p;
                acc += p;
            }
            for (int off = 1; off < 16; off <<= 1)
                acc += __shfl_xor(acc, off);
            li[r] = li[r] * alpha[r] + acc;
            for (int nb = 0; nb < 4; ++nb) oacc[nb][r] *= alpha[r];
        }

        // ---- P (C layout) -> LDS -> A-frag layout (wave-private rows) ----
        for (int nb = 0; nb < 4; ++nb)
            for (int r = 0; r < 4; ++r) {
                bf16 hv = __float2bfloat16(sacc[nb][r]);
                Ps[(wave * 16 + q * 4 + r) * FS + nb * 16 + m] = *(short*)&hv;
            }
        short8 pa0 = *(const short8*)&Ps[(wave * 16 + m) * FS + q * 8];
        short8 pa1 = *(const short8*)&Ps[(wave * 16 + m) * FS + 32 + q * 8];

        // ---- O += P V  (B-frag rows = d, k = key, from V^T tile) ----
        for (int nb = 0; nb < 4; ++nb) {
            short8 vf0 = *(const short8*)&Vs[(nb * 16 + m) * FS + q * 8];
            short8 vf1 = *(const short8*)&Vs[(nb * 16 + m) * FS + 32 + q * 8];
            oacc[nb] = MFMA16(pa0, vf0, oacc[nb]);
            oacc[nb] = MFMA16(pa1, vf1, oacc[nb]);
        }
    }

    // ---- normalize + write ctx [b, s, h*64+d] ----
    for (int r = 0; r < 4; ++r) {
        float inv = 1.f / li[r];
        int srowg = qt * 64 + wave * 16 + q * 4 + r;
        for (int nb = 0; nb < 4; ++nb)
            ctx[(b * 2048 + srowg) * 1024 + h * 64 + nb * 16 + m] =
                __float2bfloat16(oacc[nb][r] * inv);
    }
}

// ---------------------------------------------------------------------------
// Kernel 3: output projection (out = ctx * Wo^T), prefetch pipeline;
// store dtype per flag.
// ---------------------------------------------------------------------------
__global__ __launch_bounds__(256) void gemm_out(
    const bf16* __restrict__ A, const bf16* __restrict__ W,
    void* __restrict__ out, const unsigned int* __restrict__ flag)
{
    __shared__ __align__(16) short As[64 * 40];
    __shared__ __align__(16) short Ws[64 * 40];

    const int m0 = blockIdx.x * 64;
    const int n0 = blockIdx.y * 64;
    const int tid  = threadIdx.x;
    const int lane = tid & 63;
    const int wave = tid >> 6;
    const int wr = wave >> 1, wc = wave & 1;
    const int srow = tid >> 2, sseg = tid & 3;
    const int fr = lane & 15, fq = lane >> 4;
    const unsigned int fl = flag[0];

    const bf16* Arow = A + (m0 + srow) * 1024 + sseg * 8;
    const bf16* Wrow = W + (n0 + srow) * 1024 + sseg * 8;

    f32x4 acc00 = {0.f,0.f,0.f,0.f}, acc01 = {0.f,0.f,0.f,0.f};
    f32x4 acc10 = {0.f,0.f,0.f,0.f}, acc11 = {0.f,0.f,0.f,0.f};

    short8 paa = *(const short8*)(Arow);
    short8 pwb = *(const short8*)(Wrow);

    for (int k0 = 0; k0 < 1024; k0 += 32) {
        __syncthreads();
        *(short8*)&As[srow * 40 + sseg * 8] = paa;
        *(short8*)&Ws[srow * 40 + sseg * 8] = pwb;
        __syncthreads();
        if (k0 + 32 < 1024) {
            paa = *(const short8*)(Arow + k0 + 32);
            pwb = *(const short8*)(Wrow + k0 + 32);
        }
        short8 a0 = *(const short8*)&As[(wr * 32 +      fr) * 40 + fq * 8];
        short8 a1 = *(const short8*)&As[(wr * 32 + 16 + fr) * 40 + fq * 8];
        short8 b0 = *(const short8*)&Ws[(wc * 32 +      fr) * 40 + fq * 8];
        short8 b1 = *(const short8*)&Ws[(wc * 32 + 16 + fr) * 40 + fq * 8];
        acc00 = MFMA16(a0, b0, acc00);
        acc01 = MFMA16(a0, b1, acc01);
        acc10 = MFMA16(a1, b0, acc10);
        acc11 = MFMA16(a1, b1, acc11);
    }

    for (int i = 0; i < 2; ++i)
        for (int j = 0; j < 2; ++j) {
            f32x4 a = (i == 0) ? ((j == 0) ? acc00 : acc01)
                               : ((j == 0) ? acc10 : acc11);
            for (int r = 0; r < 4; ++r) {
                int gm = m0 + wr * 32 + i * 16 + fq * 4 + r;
                int gn = n0 + wc * 32 + j * 16 + fr;
                int idx = gm * 1024 + gn;
                if (fl == 0u) ((bf16*)out)[idx]  = __float2bfloat16(a[r]);
                else          ((float*)out)[idx] = a[r];
            }
        }
}

// ---------------------------------------------------------------------------
extern "C" void kernel_launch(void* const* d_in, const int* in_sizes, int n_in,
                              void* d_out, int out_size, void* d_ws, size_t ws_size,
                              hipStream_t stream)
{
    const void* x_raw  = d_in[0];
    const void* Wq_raw = d_in[1];
    const void* Wk_raw = d_in[2];
    const void* Wv_raw = d_in[3];
    const void* Wo_raw = d_in[4];
    const int*  pos    = (const int*)d_in[5];

    char* ws = (char*)d_ws;
    unsigned int* flag = (unsigned int*)ws;                   // 256 B
    bf16* Xc  = (bf16*)(ws + 256);                            // 8 MB
    bf16* Wqc = (bf16*)(ws + 256 + 8388608);                  // 2 MB each
    bf16* Wkc = (bf16*)(ws + 256 + 8388608 + 2097152);
    bf16* Wvc = (bf16*)(ws + 256 + 8388608 + 2 * 2097152);
    bf16* Woc = (bf16*)(ws + 256 + 8388608 + 3 * 2097152);
    bf16* Qb  = (bf16*)(ws + 256 + 8388608 + 4 * 2097152);    // 8 MB each
    bf16* Kb  = Qb + 4194304;
    bf16* Vt  = Kb + 4194304;
    bf16* ctx = Vt + 4194304;

    dtype_probe<<<1, 256, 0, stream>>>((const unsigned short*)x_raw, flag);

    convert_all<<<16384, 256, 0, stream>>>(
        x_raw, Wq_raw, Wk_raw, Wv_raw, Wo_raw,
        (unsigned int*)Xc, (unsigned int*)Wqc, (unsigned int*)Wkc,
        (unsigned int*)Wvc, (unsigned int*)Woc, flag);

    gemm_qkv_rope<<<dim3(64, 48), 256, 0, stream>>>(Xc, Wqc, Wkc, Wvc, pos, Qb, Kb, Vt);
    flash_attn<<<dim3(32, 16, 2), 256, 0, stream>>>(Qb, Kb, Vt, ctx);
    gemm_out<<<dim3(64, 16), 256, 0, stream>>>(ctx, Woc, d_out, flag);
}